// Round 7
// baseline (564.991 us; speedup 1.0000x reference)
//
#include <hip/hip_runtime.h>
#include <cstdint>
#include <cstddef>

#define N_NODES 100000
#define N_EDGES 1600000

// ---- bucketed counting-sort CSR parameters ----
constexpr int NPB = 512;                               // nodes per bucket (2^9)
constexpr int NBUCK = (N_NODES + NPB - 1) / NPB;       // 196
constexpr int EPB = 8192;                              // edges per block in B1/B2
constexpr int NCHUNK = (N_EDGES + EPB - 1) / EPB;      // 196

typedef _Float16 half8 __attribute__((ext_vector_type(8)));
typedef _Float16 half2v __attribute__((ext_vector_type(2)));
typedef float f32x4 __attribute__((ext_vector_type(4)));

// ================================================================= CSR build
__global__ __launch_bounds__(256) void b1_hist(const int* __restrict__ dst,
                                               int* __restrict__ bbc) {
    __shared__ int hist[NBUCK];
    int t = threadIdx.x;
    if (t < NBUCK) hist[t] = 0;
    __syncthreads();
    int base = blockIdx.x * EPB;
#pragma unroll
    for (int i = 0; i < EPB / 256; ++i) {
        int e = base + i * 256 + t;
        if (e < N_EDGES) atomicAdd(&hist[dst[e] >> 9], 1);
    }
    __syncthreads();
    if (t < NBUCK) bbc[t * NCHUNK + blockIdx.x] = hist[t];
}

__global__ void b_scan(int* __restrict__ bbc, int* __restrict__ bucketOff,
                       int* __restrict__ rowStart) {
    __shared__ int tot[NBUCK];
    int t = threadIdx.x;
    if (t < NBUCK) {
        int run = 0;
        for (int blk = 0; blk < NCHUNK; ++blk) {
            int idx = t * NCHUNK + blk;
            int c = bbc[idx];
            bbc[idx] = run;
            run += c;
        }
        tot[t] = run;
    }
    __syncthreads();
    if (t == 0) {
        int acc = 0;
        for (int b = 0; b < NBUCK; ++b) {
            bucketOff[b] = acc;
            acc += tot[b];
        }
        bucketOff[NBUCK] = acc;
        rowStart[N_NODES] = acc;
    }
}

__global__ __launch_bounds__(256) void b2_scatter(const int* __restrict__ src,
                                                  const int* __restrict__ dst,
                                                  const int* __restrict__ bbc,
                                                  const int* __restrict__ bucketOff,
                                                  int* __restrict__ staged) {
    __shared__ int cnt[NBUCK];
    __shared__ int base[NBUCK];
    int t = threadIdx.x;
    if (t < NBUCK) {
        cnt[t] = 0;
        base[t] = bucketOff[t] + bbc[t * NCHUNK + blockIdx.x];
    }
    __syncthreads();
    int ebase = blockIdx.x * EPB;
#pragma unroll
    for (int i = 0; i < EPB / 256; ++i) {
        int e = ebase + i * 256 + t;
        if (e < N_EDGES) {
            int d = dst[e];
            int b = d >> 9;
            int r = atomicAdd(&cnt[b], 1);
            staged[base[b] + r] = ((d & 511) << 17) | src[e];
        }
    }
}

__global__ __launch_bounds__(256) void b3_sort(const int* __restrict__ staged,
                                               const int* __restrict__ bucketOff,
                                               int* __restrict__ rowStart,
                                               float* __restrict__ normv,
                                               int* __restrict__ colIdx) {
    __shared__ int hist[NPB];
    __shared__ int sc0[NPB], sc1[NPB];
    __shared__ int cursor[NPB];
    int t = threadIdx.x;
    int b = blockIdx.x;
    int e0 = bucketOff[b], e1 = bucketOff[b + 1];
    int ne = e1 - e0;
    int node0 = b * NPB;
    int nn = min(NPB, N_NODES - node0);

    for (int j = t; j < NPB; j += 256) hist[j] = 0;
    __syncthreads();
    for (int idx = t; idx < ne; idx += 256)
        atomicAdd(&hist[staged[e0 + idx] >> 17], 1);
    __syncthreads();
    for (int j = t; j < NPB; j += 256) sc0[j] = hist[j];
    __syncthreads();
    int* s = sc0;
    int* d = sc1;
    for (int off = 1; off < NPB; off <<= 1) {
        for (int j = t; j < NPB; j += 256) d[j] = s[j] + (j >= off ? s[j - off] : 0);
        __syncthreads();
        int* tmp = s; s = d; d = tmp;
    }
    for (int j = t; j < NPB; j += 256) {
        int excl = s[j] - hist[j];
        cursor[j] = excl;
        if (j < nn) {
            rowStart[node0 + j] = e0 + excl;
            normv[node0 + j] = (float)(1.0 / sqrt((double)(hist[j] + 1)));
        }
    }
    __syncthreads();
    for (int idx = t; idx < ne; idx += 256) {
        int v = staged[e0 + idx];
        int dl = v >> 17;
        int sn = v & 0x1FFFF;
        int r = atomicAdd(&cursor[dl], 1);
        colIdx[e0 + r] = sn;
    }
}

// ================================================== weight prep (tiny)
__global__ void wc_kernel(const float* __restrict__ Wp, const float* __restrict__ bp,
                          const float* __restrict__ W1, float* __restrict__ Wc,
                          float* __restrict__ bc) {
    int r = blockIdx.x;
    int cc = threadIdx.x;
    float acc = 0.f;
    if (r < 256) {
        for (int k = 0; k < 128; ++k) acc = fmaf(Wp[r * 128 + k], W1[k * 128 + cc], acc);
        Wc[r * 128 + cc] = acc;
    } else {
        for (int k = 0; k < 128; ++k) acc = fmaf(bp[k], W1[k * 128 + cc], acc);
        bc[cc] = acc;
    }
}

// transpose + f16 hi/lo split: W[K][128] -> Oh/Ol[128][K]
__global__ void tsplit_kernel(const float* __restrict__ W, _Float16* __restrict__ Oh,
                              _Float16* __restrict__ Ol, int K) {
    int id = blockIdx.x * 256 + threadIdx.x;
    if (id >= K * 128) return;
    int n = id / K;
    int k = id - n * K;
    float v = W[k * 128 + n];
    _Float16 h = (_Float16)v;
    Oh[id] = h;
    Ol[id] = (_Float16)(v - (float)h);
}

// =============================================== split-f16 MFMA GEMM, no LDS
// C[r][c] = (sum_k A[r][k]*B[k][c] + bias[c]) * scale[r], C stored fp16 or fp32.
// 64 rows per block, 16 rows per wave (one 16x16 M-tile). All operands
// fragment-loaded from global; per K-iter the full B fragment set (8 nt x hi/lo
// = 64 VGPRs) is preloaded so all 18 loads are in flight before one waitcnt.
// No LDS, no barriers.
template <bool AF16>
__global__ __launch_bounds__(256) void mfma_gemm(const float* __restrict__ Af,
                                                 const _Float16* __restrict__ Ah,
                                                 const _Float16* __restrict__ Bth,
                                                 const _Float16* __restrict__ Btl,
                                                 const float* __restrict__ bias,
                                                 const float* __restrict__ scale,
                                                 float* __restrict__ Cf,
                                                 _Float16* __restrict__ Ch,
                                                 int M, int K) {
    const int t = threadIdx.x;
    const int w = t >> 6;
    const int lane = t & 63;
    const int q = lane >> 4;       // quad 0..3 -> k = q*8 + j
    const int mr = lane & 15;      // row/col within 16
    const int row0 = blockIdx.x * 64 + w * 16;

    int ar = row0 + mr;
    if (ar >= M) ar = M - 1;       // clamped; stores are guarded

    f32x4 acc[8];
#pragma unroll
    for (int nt = 0; nt < 8; ++nt) acc[nt] = (f32x4){0.f, 0.f, 0.f, 0.f};

    const float*    apf = Af ? Af + (size_t)ar * K + q * 8 : nullptr;
    const _Float16* aph = Ah ? Ah + (size_t)ar * K + q * 8 : nullptr;
    const _Float16* bhp = Bth + (size_t)mr * K + q * 8;
    const _Float16* blp = Btl + (size_t)mr * K + q * 8;
    const size_t nstride = (size_t)16 * K;

    for (int k0 = 0; k0 < K; k0 += 32) {
        // ---- preload the full fragment set for this K-slab ----
        half8 bh[8], bl[8];
#pragma unroll
        for (int nt = 0; nt < 8; ++nt) {
            bh[nt] = *(const half8*)(bhp + nt * nstride);
            bl[nt] = *(const half8*)(blp + nt * nstride);
        }
        half8 ah, al;
        if constexpr (AF16) {
            ah = *(const half8*)aph;
            aph += 32;
        } else {
            float4 v0 = *(const float4*)apf;
            float4 v1 = *(const float4*)(apf + 4);
            apf += 32;
            float av[8] = {v0.x, v0.y, v0.z, v0.w, v1.x, v1.y, v1.z, v1.w};
#pragma unroll
            for (int j = 0; j < 8; ++j) {
                _Float16 h = (_Float16)av[j];
                ah[j] = h;
                al[j] = (_Float16)(av[j] - (float)h);
            }
        }
        bhp += 32;
        blp += 32;

        // ---- MFMA burst (all independent across nt) ----
#pragma unroll
        for (int nt = 0; nt < 8; ++nt) {
            acc[nt] = __builtin_amdgcn_mfma_f32_16x16x32_f16(ah, bh[nt], acc[nt], 0, 0, 0);
            acc[nt] = __builtin_amdgcn_mfma_f32_16x16x32_f16(ah, bl[nt], acc[nt], 0, 0, 0);
            if constexpr (!AF16)
                acc[nt] = __builtin_amdgcn_mfma_f32_16x16x32_f16(al, bh[nt], acc[nt], 0, 0, 0);
        }
    }

    // epilogue: C/D layout col=lane&15 (=mr), row=q*4+reg
#pragma unroll
    for (int r = 0; r < 4; ++r) {
        int row = row0 + q * 4 + r;
        if (row >= M) continue;
        float sc = scale[row];
#pragma unroll
        for (int nt = 0; nt < 8; ++nt) {
            int col = nt * 16 + mr;
            float bv = bias ? bias[col] : 0.f;
            float val = (acc[nt][r] + bv) * sc;
            if (Ch) Ch[(size_t)row * 128 + col] = (_Float16)val;
            else    Cf[(size_t)row * 128 + col] = val;
        }
    }
}

// ------------------------------------------------------------- aggregation
// zs fp16 pre-scaled by norm[row]. out = maybe_relu(norm[i]*(sum zs[src]+zs[i])+b)
__global__ __launch_bounds__(256) void agg_kernel(const _Float16* __restrict__ zs,
                                                  const int* __restrict__ rowStart,
                                                  const int* __restrict__ colIdx,
                                                  const float* __restrict__ normv,
                                                  const float* __restrict__ bias,
                                                  float* __restrict__ outF,
                                                  _Float16* __restrict__ outH,
                                                  int doRelu) {
    int wid = (blockIdx.x * 256 + threadIdx.x) >> 6;
    int lane = threadIdx.x & 63;
    if (wid >= N_NODES) return;
    int s0 = rowStart[wid];
    int s1 = rowStart[wid + 1];
    const int c = lane * 2;
    const _Float16* zc = zs + c;

    float2 a0 = make_float2(0.f, 0.f), a1 = a0, a2 = a0, a3 = a0;
    int e = s0;
    for (; e + 8 <= s1; e += 8) {
        int i0 = colIdx[e + 0], i1 = colIdx[e + 1], i2 = colIdx[e + 2], i3 = colIdx[e + 3];
        int i4 = colIdx[e + 4], i5 = colIdx[e + 5], i6 = colIdx[e + 6], i7 = colIdx[e + 7];
        half2v v0 = *(const half2v*)(zc + (size_t)i0 * 128);
        half2v v1 = *(const half2v*)(zc + (size_t)i1 * 128);
        half2v v2 = *(const half2v*)(zc + (size_t)i2 * 128);
        half2v v3 = *(const half2v*)(zc + (size_t)i3 * 128);
        half2v v4 = *(const half2v*)(zc + (size_t)i4 * 128);
        half2v v5 = *(const half2v*)(zc + (size_t)i5 * 128);
        half2v v6 = *(const half2v*)(zc + (size_t)i6 * 128);
        half2v v7 = *(const half2v*)(zc + (size_t)i7 * 128);
        a0.x += (float)v0[0] + (float)v4[0]; a0.y += (float)v0[1] + (float)v4[1];
        a1.x += (float)v1[0] + (float)v5[0]; a1.y += (float)v1[1] + (float)v5[1];
        a2.x += (float)v2[0] + (float)v6[0]; a2.y += (float)v2[1] + (float)v6[1];
        a3.x += (float)v3[0] + (float)v7[0]; a3.y += (float)v3[1] + (float)v7[1];
    }
    if (e + 4 <= s1) {
        int i0 = colIdx[e + 0], i1 = colIdx[e + 1], i2 = colIdx[e + 2], i3 = colIdx[e + 3];
        half2v v0 = *(const half2v*)(zc + (size_t)i0 * 128);
        half2v v1 = *(const half2v*)(zc + (size_t)i1 * 128);
        half2v v2 = *(const half2v*)(zc + (size_t)i2 * 128);
        half2v v3 = *(const half2v*)(zc + (size_t)i3 * 128);
        a0.x += (float)v0[0]; a0.y += (float)v0[1];
        a1.x += (float)v1[0]; a1.y += (float)v1[1];
        a2.x += (float)v2[0]; a2.y += (float)v2[1];
        a3.x += (float)v3[0]; a3.y += (float)v3[1];
        e += 4;
    }
    for (; e < s1; ++e) {
        int i0 = colIdx[e];
        half2v v0 = *(const half2v*)(zc + (size_t)i0 * 128);
        a0.x += (float)v0[0]; a0.y += (float)v0[1];
    }

    half2v self = *(const half2v*)(zc + (size_t)wid * 128);
    float sx = (a0.x + a1.x) + (a2.x + a3.x) + (float)self[0];
    float sy = (a0.y + a1.y) + (a2.y + a3.y) + (float)self[1];
    float nd = normv[wid];
    float2 bv = *(const float2*)(bias + c);
    float ox = fmaf(nd, sx, bv.x);
    float oy = fmaf(nd, sy, bv.y);
    if (doRelu) {
        ox = fmaxf(ox, 0.f);
        oy = fmaxf(oy, 0.f);
    }
    if (outH) {
        half2v o;
        o[0] = (_Float16)ox;
        o[1] = (_Float16)oy;
        *(half2v*)(outH + (size_t)wid * 128 + c) = o;
    } else {
        *(float2*)(outF + (size_t)wid * 128 + c) = make_float2(ox, oy);
    }
}

// ---------------------------------------------------------------- launcher
extern "C" void kernel_launch(void* const* d_in, const int* in_sizes, int n_in,
                              void* d_out, int out_size, void* d_ws, size_t ws_size,
                              hipStream_t stream) {
    const float* x  = (const float*)d_in[0];
    const int* ei   = (const int*)d_in[1];
    const float* Wp = (const float*)d_in[2];
    const float* bp = (const float*)d_in[3];
    const float* W1 = (const float*)d_in[4];
    const float* b1 = (const float*)d_in[5];
    const float* W2 = (const float*)d_in[6];
    const float* b2 = (const float*)d_in[7];
    float* out = (float*)d_out;

    const int* srcIdx = ei;
    const int* dstIdx = ei + N_EDGES;

    size_t off = 0;
    auto alloc = [&](size_t bytes) -> void* {
        void* p = (char*)d_ws + off;
        off += (bytes + 511) & ~(size_t)511;
        return p;
    };
    int* rowStart   = (int*)alloc((size_t)(N_NODES + 1) * 4);
    int* colIdx     = (int*)alloc((size_t)N_EDGES * 4);
    int* staged     = (int*)alloc((size_t)N_EDGES * 4);
    int* bbc        = (int*)alloc((size_t)NBUCK * NCHUNK * 4);
    int* bucketOff  = (int*)alloc((size_t)(NBUCK + 1) * 4);
    float* normv    = (float*)alloc((size_t)N_NODES * 4);
    float* Wc       = (float*)alloc((size_t)256 * 128 * 4);
    float* bc       = (float*)alloc((size_t)128 * 4);
    _Float16* Wcth  = (_Float16*)alloc((size_t)128 * 256 * 2);
    _Float16* Wctl  = (_Float16*)alloc((size_t)128 * 256 * 2);
    _Float16* W2th  = (_Float16*)alloc((size_t)128 * 128 * 2);
    _Float16* W2tl  = (_Float16*)alloc((size_t)128 * 128 * 2);
    _Float16* zA    = (_Float16*)alloc((size_t)N_NODES * 128 * 2);
    _Float16* zB    = (_Float16*)alloc((size_t)N_NODES * 128 * 2);

    const int GB = (N_NODES + 63) / 64;    // 1563 (64 rows/block)
    const int AB = (N_NODES + 3) / 4;      // 25000

    // ---- CSR build (bucketed counting sort) ----
    b1_hist<<<NCHUNK, 256, 0, stream>>>(dstIdx, bbc);
    b_scan<<<1, 256, 0, stream>>>(bbc, bucketOff, rowStart);
    b2_scatter<<<NCHUNK, 256, 0, stream>>>(srcIdx, dstIdx, bbc, bucketOff, staged);
    b3_sort<<<NBUCK, 256, 0, stream>>>(staged, bucketOff, rowStart, normv, colIdx);

    // ---- weight prep ----
    wc_kernel<<<257, 128, 0, stream>>>(Wp, bp, W1, Wc, bc);
    tsplit_kernel<<<(256 * 128 + 255) / 256, 256, 0, stream>>>(Wc, Wcth, Wctl, 256);
    tsplit_kernel<<<(128 * 128 + 255) / 256, 256, 0, stream>>>(W2, W2th, W2tl, 128);

    // ---- pipeline (all intermediates fp16, pre-scaled by norm) ----
    // zA = f16[(x @ Wc + bc) * norm]
    mfma_gemm<false><<<GB, 256, 0, stream>>>(x, nullptr, Wcth, Wctl, bc, normv,
                                             nullptr, zA, N_NODES, 256);
    // zB = f16[relu(norm*(sum zA[src] + zA[self]) + b1)]
    agg_kernel<<<AB, 256, 0, stream>>>(zA, rowStart, colIdx, normv, b1, nullptr, zB, 1);
    // zA (reused) = f16[(zB @ W2) * norm]   — A fp16, 2-product path
    mfma_gemm<true><<<GB, 256, 0, stream>>>(nullptr, zB, W2th, W2tl, nullptr, normv,
                                            nullptr, zA, N_NODES, 128);
    // out = fp32[norm*(sum zA[src] + zA[self]) + b2]
    agg_kernel<<<AB, 256, 0, stream>>>(zA, rowStart, colIdx, normv, b2, out, nullptr, 0);
}

// Round 8
// 477.229 us; speedup vs baseline: 1.1839x; 1.1839x over previous
//
#include <hip/hip_runtime.h>
#include <cstdint>
#include <cstddef>

#define N_NODES 100000
#define N_EDGES 1600000

// ---- bucketed counting-sort CSR parameters ----
constexpr int NPB = 512;                               // nodes per bucket (2^9)
constexpr int NBUCK = (N_NODES + NPB - 1) / NPB;       // 196
constexpr int EPB = 8192;                              // edges per block in B1/B2
constexpr int NCHUNK = (N_EDGES + EPB - 1) / EPB;      // 196

typedef _Float16 half8 __attribute__((ext_vector_type(8)));
typedef _Float16 half2v __attribute__((ext_vector_type(2)));
typedef float f32x4 __attribute__((ext_vector_type(4)));

// ================================================================= CSR build
__global__ __launch_bounds__(256) void b1_hist(const int* __restrict__ dst,
                                               int* __restrict__ bbc) {
    __shared__ int hist[NBUCK];
    int t = threadIdx.x;
    if (t < NBUCK) hist[t] = 0;
    __syncthreads();
    int base = blockIdx.x * EPB;
#pragma unroll
    for (int i = 0; i < EPB / 256; ++i) {
        int e = base + i * 256 + t;
        if (e < N_EDGES) atomicAdd(&hist[dst[e] >> 9], 1);
    }
    __syncthreads();
    if (t < NBUCK) bbc[t * NCHUNK + blockIdx.x] = hist[t];
}

__global__ void b_scan(int* __restrict__ bbc, int* __restrict__ bucketOff,
                       int* __restrict__ rowStart) {
    __shared__ int tot[NBUCK];
    int t = threadIdx.x;
    if (t < NBUCK) {
        int run = 0;
        for (int blk = 0; blk < NCHUNK; ++blk) {
            int idx = t * NCHUNK + blk;
            int c = bbc[idx];
            bbc[idx] = run;
            run += c;
        }
        tot[t] = run;
    }
    __syncthreads();
    if (t == 0) {
        int acc = 0;
        for (int b = 0; b < NBUCK; ++b) {
            bucketOff[b] = acc;
            acc += tot[b];
        }
        bucketOff[NBUCK] = acc;
        rowStart[N_NODES] = acc;
    }
}

__global__ __launch_bounds__(256) void b2_scatter(const int* __restrict__ src,
                                                  const int* __restrict__ dst,
                                                  const int* __restrict__ bbc,
                                                  const int* __restrict__ bucketOff,
                                                  int* __restrict__ staged) {
    __shared__ int cnt[NBUCK];
    __shared__ int base[NBUCK];
    int t = threadIdx.x;
    if (t < NBUCK) {
        cnt[t] = 0;
        base[t] = bucketOff[t] + bbc[t * NCHUNK + blockIdx.x];
    }
    __syncthreads();
    int ebase = blockIdx.x * EPB;
#pragma unroll
    for (int i = 0; i < EPB / 256; ++i) {
        int e = ebase + i * 256 + t;
        if (e < N_EDGES) {
            int d = dst[e];
            int b = d >> 9;
            int r = atomicAdd(&cnt[b], 1);
            staged[base[b] + r] = ((d & 511) << 17) | src[e];
        }
    }
}

__global__ __launch_bounds__(256) void b3_sort(const int* __restrict__ staged,
                                               const int* __restrict__ bucketOff,
                                               int* __restrict__ rowStart,
                                               float* __restrict__ normv,
                                               int* __restrict__ colIdx) {
    __shared__ int hist[NPB];
    __shared__ int sc0[NPB], sc1[NPB];
    __shared__ int cursor[NPB];
    int t = threadIdx.x;
    int b = blockIdx.x;
    int e0 = bucketOff[b], e1 = bucketOff[b + 1];
    int ne = e1 - e0;
    int node0 = b * NPB;
    int nn = min(NPB, N_NODES - node0);

    for (int j = t; j < NPB; j += 256) hist[j] = 0;
    __syncthreads();
    for (int idx = t; idx < ne; idx += 256)
        atomicAdd(&hist[staged[e0 + idx] >> 17], 1);
    __syncthreads();
    for (int j = t; j < NPB; j += 256) sc0[j] = hist[j];
    __syncthreads();
    int* s = sc0;
    int* d = sc1;
    for (int off = 1; off < NPB; off <<= 1) {
        for (int j = t; j < NPB; j += 256) d[j] = s[j] + (j >= off ? s[j - off] : 0);
        __syncthreads();
        int* tmp = s; s = d; d = tmp;
    }
    for (int j = t; j < NPB; j += 256) {
        int excl = s[j] - hist[j];
        cursor[j] = excl;
        if (j < nn) {
            rowStart[node0 + j] = e0 + excl;
            normv[node0 + j] = (float)(1.0 / sqrt((double)(hist[j] + 1)));
        }
    }
    __syncthreads();
    for (int idx = t; idx < ne; idx += 256) {
        int v = staged[e0 + idx];
        int dl = v >> 17;
        int sn = v & 0x1FFFF;
        int r = atomicAdd(&cursor[dl], 1);
        colIdx[e0 + r] = sn;
    }
}

// ================================================== weight prep (tiny)
__global__ void wc_kernel(const float* __restrict__ Wp, const float* __restrict__ bp,
                          const float* __restrict__ W1, float* __restrict__ Wc,
                          float* __restrict__ bc) {
    int r = blockIdx.x;
    int cc = threadIdx.x;
    float acc = 0.f;
    if (r < 256) {
        for (int k = 0; k < 128; ++k) acc = fmaf(Wp[r * 128 + k], W1[k * 128 + cc], acc);
        Wc[r * 128 + cc] = acc;
    } else {
        for (int k = 0; k < 128; ++k) acc = fmaf(bp[k], W1[k * 128 + cc], acc);
        bc[cc] = acc;
    }
}

// transpose + f16 hi/lo split: W[K][128] -> Oh/Ol[128][K]
__global__ void tsplit_kernel(const float* __restrict__ W, _Float16* __restrict__ Oh,
                              _Float16* __restrict__ Ol, int K) {
    int id = blockIdx.x * 256 + threadIdx.x;
    if (id >= K * 128) return;
    int n = id / K;
    int k = id - n * K;
    float v = W[k * 128 + n];
    _Float16 h = (_Float16)v;
    Oh[id] = h;
    Ol[id] = (_Float16)(v - (float)h);
}

// =============================================== split-f16 MFMA GEMM (hybrid)
// C[r][c] = (sum_k A[r][k]*B[k][c] + bias[c]) * scale[r], C stored fp16 or fp32.
// 128 rows/block, 4 waves in 2x2; wave = 64 rows x 64 cols = 4mt x 4nt 16x16 tiles.
// B hi/lo double-buffered in LDS (pad stride 40 -> 2-way/free), staged via regs,
// ONE barrier per K-slab; B global loads issued before MFMA burst to overlap.
// A fragments direct from global with explicit next-slab prefetch registers.
template <bool AF16, int K>
__global__ __launch_bounds__(256) void mfma_gemm(const float* __restrict__ Af,
                                                 const _Float16* __restrict__ Ah,
                                                 const _Float16* __restrict__ Bth,
                                                 const _Float16* __restrict__ Btl,
                                                 const float* __restrict__ bias,
                                                 const float* __restrict__ scale,
                                                 float* __restrict__ Cf,
                                                 _Float16* __restrict__ Ch,
                                                 int M) {
    constexpr int NSLAB = K / 32;
    __shared__ _Float16 sBh[2][128 * 40];
    __shared__ _Float16 sBl[2][128 * 40];

    const int t = threadIdx.x;
    const int w = t >> 6;
    const int wm = w & 1;          // wave row 0..1
    const int wn = w >> 1;         // wave col 0..1
    const int lane = t & 63;
    const int q = lane >> 4;       // quad -> k = q*8 + j
    const int mr = lane & 15;
    const int row0 = blockIdx.x * 128 + wm * 64;
    const int col0 = wn * 64;

    // ---- B staging assignment: lane covers n = t>>1, k-halves [seg*16, seg*16+16)
    const int sn = t >> 1;
    const int sseg = t & 1;
    const _Float16* gBh = Bth + (size_t)sn * K + sseg * 16;
    const _Float16* gBl = Btl + (size_t)sn * K + sseg * 16;
    const int swoff = sn * 40 + sseg * 16;

    // ---- A row addresses (clamped; stores guarded)
    int arow[4];
#pragma unroll
    for (int mt = 0; mt < 4; ++mt) {
        int r = row0 + mt * 16 + mr;
        arow[mt] = (r < M) ? r : (M - 1);
    }

    f32x4 acc[4][4];
#pragma unroll
    for (int mt = 0; mt < 4; ++mt)
#pragma unroll
        for (int nt = 0; nt < 4; ++nt) acc[mt][nt] = (f32x4){0.f, 0.f, 0.f, 0.f};

    // ---- prologue: stage slab 0 of B; prefetch A slab 0
    {
        half8 h0 = *(const half8*)(gBh);
        half8 h1 = *(const half8*)(gBh + 8);
        half8 l0 = *(const half8*)(gBl);
        half8 l1 = *(const half8*)(gBl + 8);
        *(half8*)&sBh[0][swoff] = h0;
        *(half8*)&sBh[0][swoff + 8] = h1;
        *(half8*)&sBl[0][swoff] = l0;
        *(half8*)&sBl[0][swoff + 8] = l1;
    }
    float4 aPre0[4], aPre1[4];   // fp32 path prefetch
    half8  aPreH[4];             // f16 path prefetch
#pragma unroll
    for (int mt = 0; mt < 4; ++mt) {
        if constexpr (AF16) {
            aPreH[mt] = *(const half8*)(Ah + (size_t)arow[mt] * K + q * 8);
        } else {
            const float* ap = Af + (size_t)arow[mt] * K + q * 8;
            aPre0[mt] = *(const float4*)ap;
            aPre1[mt] = *(const float4*)(ap + 4);
        }
    }
    __syncthreads();

#pragma unroll
    for (int s = 0; s < NSLAB; ++s) {
        const int cur = s & 1;
        const int nxt = 1 - cur;

        // ---- convert/settle current A fragments
        half8 ah[4], al[4];
#pragma unroll
        for (int mt = 0; mt < 4; ++mt) {
            if constexpr (AF16) {
                ah[mt] = aPreH[mt];
            } else {
                float av[8] = {aPre0[mt].x, aPre0[mt].y, aPre0[mt].z, aPre0[mt].w,
                               aPre1[mt].x, aPre1[mt].y, aPre1[mt].z, aPre1[mt].w};
#pragma unroll
                for (int j = 0; j < 8; ++j) {
                    _Float16 h = (_Float16)av[j];
                    ah[mt][j] = h;
                    al[mt][j] = (_Float16)(av[j] - (float)h);
                }
            }
        }

        // ---- issue next-slab global loads (fly under the MFMA burst)
        half8 nh0, nh1, nl0, nl1;
        if (s + 1 < NSLAB) {
            const int ko = (s + 1) * 32;
            nh0 = *(const half8*)(gBh + ko);
            nh1 = *(const half8*)(gBh + ko + 8);
            nl0 = *(const half8*)(gBl + ko);
            nl1 = *(const half8*)(gBl + ko + 8);
#pragma unroll
            for (int mt = 0; mt < 4; ++mt) {
                if constexpr (AF16) {
                    aPreH[mt] = *(const half8*)(Ah + (size_t)arow[mt] * K + ko + q * 8);
                } else {
                    const float* ap = Af + (size_t)arow[mt] * K + ko + q * 8;
                    aPre0[mt] = *(const float4*)ap;
                    aPre1[mt] = *(const float4*)(ap + 4);
                }
            }
        }

        // ---- B fragments from LDS (pad-40: conflict-free)
        half8 bh[4], bl[4];
#pragma unroll
        for (int nt = 0; nt < 4; ++nt) {
            int n = col0 + nt * 16 + mr;
            bh[nt] = *(half8*)&sBh[cur][n * 40 + q * 8];
            bl[nt] = *(half8*)&sBl[cur][n * 40 + q * 8];
        }

        // ---- MFMA burst
#pragma unroll
        for (int mt = 0; mt < 4; ++mt)
#pragma unroll
            for (int nt = 0; nt < 4; ++nt) {
                acc[mt][nt] = __builtin_amdgcn_mfma_f32_16x16x32_f16(ah[mt], bh[nt], acc[mt][nt], 0, 0, 0);
                acc[mt][nt] = __builtin_amdgcn_mfma_f32_16x16x32_f16(ah[mt], bl[nt], acc[mt][nt], 0, 0, 0);
                if constexpr (!AF16)
                    acc[mt][nt] = __builtin_amdgcn_mfma_f32_16x16x32_f16(al[mt], bh[nt], acc[mt][nt], 0, 0, 0);
            }

        // ---- commit next B slab to the other buffer, then barrier
        if (s + 1 < NSLAB) {
            *(half8*)&sBh[nxt][swoff] = nh0;
            *(half8*)&sBh[nxt][swoff + 8] = nh1;
            *(half8*)&sBl[nxt][swoff] = nl0;
            *(half8*)&sBl[nxt][swoff + 8] = nl1;
            __syncthreads();
        }
    }

    // ---- epilogue: C/D layout col=lane&15 (=mr), row=q*4+reg
#pragma unroll
    for (int mt = 0; mt < 4; ++mt) {
#pragma unroll
        for (int r = 0; r < 4; ++r) {
            int row = row0 + mt * 16 + q * 4 + r;
            if (row >= M) continue;
            float sc = scale[row];
#pragma unroll
            for (int nt = 0; nt < 4; ++nt) {
                int col = col0 + nt * 16 + mr;
                float bv = bias ? bias[col] : 0.f;
                float val = (acc[mt][nt][r] + bv) * sc;
                if (Ch) Ch[(size_t)row * 128 + col] = (_Float16)val;
                else    Cf[(size_t)row * 128 + col] = val;
            }
        }
    }
}

// ------------------------------------------------------------- aggregation
// zs fp16 pre-scaled by norm[row]. out = maybe_relu(norm[i]*(sum zs[src]+zs[i])+b)
__global__ __launch_bounds__(256) void agg_kernel(const _Float16* __restrict__ zs,
                                                  const int* __restrict__ rowStart,
                                                  const int* __restrict__ colIdx,
                                                  const float* __restrict__ normv,
                                                  const float* __restrict__ bias,
                                                  float* __restrict__ outF,
                                                  _Float16* __restrict__ outH,
                                                  int doRelu) {
    int wid = (blockIdx.x * 256 + threadIdx.x) >> 6;
    int lane = threadIdx.x & 63;
    if (wid >= N_NODES) return;
    int s0 = rowStart[wid];
    int s1 = rowStart[wid + 1];
    const int c = lane * 2;
    const _Float16* zc = zs + c;

    float2 a0 = make_float2(0.f, 0.f), a1 = a0, a2 = a0, a3 = a0;
    int e = s0;
    for (; e + 8 <= s1; e += 8) {
        int i0 = colIdx[e + 0], i1 = colIdx[e + 1], i2 = colIdx[e + 2], i3 = colIdx[e + 3];
        int i4 = colIdx[e + 4], i5 = colIdx[e + 5], i6 = colIdx[e + 6], i7 = colIdx[e + 7];
        half2v v0 = *(const half2v*)(zc + (size_t)i0 * 128);
        half2v v1 = *(const half2v*)(zc + (size_t)i1 * 128);
        half2v v2 = *(const half2v*)(zc + (size_t)i2 * 128);
        half2v v3 = *(const half2v*)(zc + (size_t)i3 * 128);
        half2v v4 = *(const half2v*)(zc + (size_t)i4 * 128);
        half2v v5 = *(const half2v*)(zc + (size_t)i5 * 128);
        half2v v6 = *(const half2v*)(zc + (size_t)i6 * 128);
        half2v v7 = *(const half2v*)(zc + (size_t)i7 * 128);
        a0.x += (float)v0[0] + (float)v4[0]; a0.y += (float)v0[1] + (float)v4[1];
        a1.x += (float)v1[0] + (float)v5[0]; a1.y += (float)v1[1] + (float)v5[1];
        a2.x += (float)v2[0] + (float)v6[0]; a2.y += (float)v2[1] + (float)v6[1];
        a3.x += (float)v3[0] + (float)v7[0]; a3.y += (float)v3[1] + (float)v7[1];
    }
    if (e + 4 <= s1) {
        int i0 = colIdx[e + 0], i1 = colIdx[e + 1], i2 = colIdx[e + 2], i3 = colIdx[e + 3];
        half2v v0 = *(const half2v*)(zc + (size_t)i0 * 128);
        half2v v1 = *(const half2v*)(zc + (size_t)i1 * 128);
        half2v v2 = *(const half2v*)(zc + (size_t)i2 * 128);
        half2v v3 = *(const half2v*)(zc + (size_t)i3 * 128);
        a0.x += (float)v0[0]; a0.y += (float)v0[1];
        a1.x += (float)v1[0]; a1.y += (float)v1[1];
        a2.x += (float)v2[0]; a2.y += (float)v2[1];
        a3.x += (float)v3[0]; a3.y += (float)v3[1];
        e += 4;
    }
    for (; e < s1; ++e) {
        int i0 = colIdx[e];
        half2v v0 = *(const half2v*)(zc + (size_t)i0 * 128);
        a0.x += (float)v0[0]; a0.y += (float)v0[1];
    }

    half2v self = *(const half2v*)(zc + (size_t)wid * 128);
    float sx = (a0.x + a1.x) + (a2.x + a3.x) + (float)self[0];
    float sy = (a0.y + a1.y) + (a2.y + a3.y) + (float)self[1];
    float nd = normv[wid];
    float2 bv = *(const float2*)(bias + c);
    float ox = fmaf(nd, sx, bv.x);
    float oy = fmaf(nd, sy, bv.y);
    if (doRelu) {
        ox = fmaxf(ox, 0.f);
        oy = fmaxf(oy, 0.f);
    }
    if (outH) {
        half2v o;
        o[0] = (_Float16)ox;
        o[1] = (_Float16)oy;
        *(half2v*)(outH + (size_t)wid * 128 + c) = o;
    } else {
        *(float2*)(outF + (size_t)wid * 128 + c) = make_float2(ox, oy);
    }
}

// ---------------------------------------------------------------- launcher
extern "C" void kernel_launch(void* const* d_in, const int* in_sizes, int n_in,
                              void* d_out, int out_size, void* d_ws, size_t ws_size,
                              hipStream_t stream) {
    const float* x  = (const float*)d_in[0];
    const int* ei   = (const int*)d_in[1];
    const float* Wp = (const float*)d_in[2];
    const float* bp = (const float*)d_in[3];
    const float* W1 = (const float*)d_in[4];
    const float* b1 = (const float*)d_in[5];
    const float* W2 = (const float*)d_in[6];
    const float* b2 = (const float*)d_in[7];
    float* out = (float*)d_out;

    const int* srcIdx = ei;
    const int* dstIdx = ei + N_EDGES;

    size_t off = 0;
    auto alloc = [&](size_t bytes) -> void* {
        void* p = (char*)d_ws + off;
        off += (bytes + 511) & ~(size_t)511;
        return p;
    };
    int* rowStart   = (int*)alloc((size_t)(N_NODES + 1) * 4);
    int* colIdx     = (int*)alloc((size_t)N_EDGES * 4);
    int* staged     = (int*)alloc((size_t)N_EDGES * 4);
    int* bbc        = (int*)alloc((size_t)NBUCK * NCHUNK * 4);
    int* bucketOff  = (int*)alloc((size_t)(NBUCK + 1) * 4);
    float* normv    = (float*)alloc((size_t)N_NODES * 4);
    float* Wc       = (float*)alloc((size_t)256 * 128 * 4);
    float* bc       = (float*)alloc((size_t)128 * 4);
    _Float16* Wcth  = (_Float16*)alloc((size_t)128 * 256 * 2);
    _Float16* Wctl  = (_Float16*)alloc((size_t)128 * 256 * 2);
    _Float16* W2th  = (_Float16*)alloc((size_t)128 * 128 * 2);
    _Float16* W2tl  = (_Float16*)alloc((size_t)128 * 128 * 2);
    _Float16* zA    = (_Float16*)alloc((size_t)N_NODES * 128 * 2);
    _Float16* zB    = (_Float16*)alloc((size_t)N_NODES * 128 * 2);

    const int GB = (N_NODES + 127) / 128;  // 782 (128 rows/block)
    const int AB = (N_NODES + 3) / 4;      // 25000

    // ---- CSR build (bucketed counting sort) ----
    b1_hist<<<NCHUNK, 256, 0, stream>>>(dstIdx, bbc);
    b_scan<<<1, 256, 0, stream>>>(bbc, bucketOff, rowStart);
    b2_scatter<<<NCHUNK, 256, 0, stream>>>(srcIdx, dstIdx, bbc, bucketOff, staged);
    b3_sort<<<NBUCK, 256, 0, stream>>>(staged, bucketOff, rowStart, normv, colIdx);

    // ---- weight prep ----
    wc_kernel<<<257, 128, 0, stream>>>(Wp, bp, W1, Wc, bc);
    tsplit_kernel<<<(256 * 128 + 255) / 256, 256, 0, stream>>>(Wc, Wcth, Wctl, 256);
    tsplit_kernel<<<(128 * 128 + 255) / 256, 256, 0, stream>>>(W2, W2th, W2tl, 128);

    // ---- pipeline (all intermediates fp16, pre-scaled by norm) ----
    // zA = f16[(x @ Wc + bc) * norm]
    mfma_gemm<false, 256><<<GB, 256, 0, stream>>>(x, nullptr, Wcth, Wctl, bc, normv,
                                                  nullptr, zA, N_NODES);
    // zB = f16[relu(norm*(sum zA[src] + zA[self]) + b1)]
    agg_kernel<<<AB, 256, 0, stream>>>(zA, rowStart, colIdx, normv, b1, nullptr, zB, 1);
    // zA (reused) = f16[(zB @ W2) * norm]   — A fp16, 2-product path
    mfma_gemm<true, 128><<<GB, 256, 0, stream>>>(nullptr, zB, W2th, W2tl, nullptr, normv,
                                                 nullptr, zA, N_NODES);
    // out = fp32[norm*(sum zA[src] + zA[self]) + b2]
    agg_kernel<<<AB, 256, 0, stream>>>(zA, rowStart, colIdx, normv, b2, out, nullptr, 0);
}

// Round 9
// 476.284 us; speedup vs baseline: 1.1862x; 1.0020x over previous
//
#include <hip/hip_runtime.h>
#include <cstdint>
#include <cstddef>

#define N_NODES 100000
#define N_EDGES 1600000

// ---- bucketed counting-sort CSR parameters ----
constexpr int NPB = 512;                               // nodes per bucket (2^9)
constexpr int NBUCK = (N_NODES + NPB - 1) / NPB;       // 196
constexpr int EPB = 8192;                              // edges per block in B1/B2
constexpr int NCHUNK = (N_EDGES + EPB - 1) / EPB;      // 196

typedef _Float16 half8 __attribute__((ext_vector_type(8)));
typedef _Float16 half2v __attribute__((ext_vector_type(2)));
typedef float f32x4 __attribute__((ext_vector_type(4)));

// ================================================================= CSR build
__global__ __launch_bounds__(256) void b1_hist(const int* __restrict__ dst,
                                               int* __restrict__ bbc) {
    __shared__ int hist[NBUCK];
    int t = threadIdx.x;
    if (t < NBUCK) hist[t] = 0;
    __syncthreads();
    int base = blockIdx.x * EPB;
#pragma unroll
    for (int i = 0; i < EPB / 256; ++i) {
        int e = base + i * 256 + t;
        if (e < N_EDGES) atomicAdd(&hist[dst[e] >> 9], 1);
    }
    __syncthreads();
    if (t < NBUCK) bbc[t * NCHUNK + blockIdx.x] = hist[t];
}

__global__ void b_scan(int* __restrict__ bbc, int* __restrict__ bucketOff,
                       int* __restrict__ rowStart) {
    __shared__ int tot[NBUCK];
    int t = threadIdx.x;
    if (t < NBUCK) {
        int run = 0;
        for (int blk = 0; blk < NCHUNK; ++blk) {
            int idx = t * NCHUNK + blk;
            int c = bbc[idx];
            bbc[idx] = run;
            run += c;
        }
        tot[t] = run;
    }
    __syncthreads();
    if (t == 0) {
        int acc = 0;
        for (int b = 0; b < NBUCK; ++b) {
            bucketOff[b] = acc;
            acc += tot[b];
        }
        bucketOff[NBUCK] = acc;
        rowStart[N_NODES] = acc;
    }
}

__global__ __launch_bounds__(256) void b2_scatter(const int* __restrict__ src,
                                                  const int* __restrict__ dst,
                                                  const int* __restrict__ bbc,
                                                  const int* __restrict__ bucketOff,
                                                  int* __restrict__ staged) {
    __shared__ int cnt[NBUCK];
    __shared__ int base[NBUCK];
    int t = threadIdx.x;
    if (t < NBUCK) {
        cnt[t] = 0;
        base[t] = bucketOff[t] + bbc[t * NCHUNK + blockIdx.x];
    }
    __syncthreads();
    int ebase = blockIdx.x * EPB;
#pragma unroll
    for (int i = 0; i < EPB / 256; ++i) {
        int e = ebase + i * 256 + t;
        if (e < N_EDGES) {
            int d = dst[e];
            int b = d >> 9;
            int r = atomicAdd(&cnt[b], 1);
            staged[base[b] + r] = ((d & 511) << 17) | src[e];
        }
    }
}

__global__ __launch_bounds__(256) void b3_sort(const int* __restrict__ staged,
                                               const int* __restrict__ bucketOff,
                                               int* __restrict__ rowStart,
                                               float* __restrict__ normv,
                                               int* __restrict__ colIdx) {
    __shared__ int hist[NPB];
    __shared__ int sc0[NPB], sc1[NPB];
    __shared__ int cursor[NPB];
    int t = threadIdx.x;
    int b = blockIdx.x;
    int e0 = bucketOff[b], e1 = bucketOff[b + 1];
    int ne = e1 - e0;
    int node0 = b * NPB;
    int nn = min(NPB, N_NODES - node0);

    for (int j = t; j < NPB; j += 256) hist[j] = 0;
    __syncthreads();
    for (int idx = t; idx < ne; idx += 256)
        atomicAdd(&hist[staged[e0 + idx] >> 17], 1);
    __syncthreads();
    for (int j = t; j < NPB; j += 256) sc0[j] = hist[j];
    __syncthreads();
    int* s = sc0;
    int* d = sc1;
    for (int off = 1; off < NPB; off <<= 1) {
        for (int j = t; j < NPB; j += 256) d[j] = s[j] + (j >= off ? s[j - off] : 0);
        __syncthreads();
        int* tmp = s; s = d; d = tmp;
    }
    for (int j = t; j < NPB; j += 256) {
        int excl = s[j] - hist[j];
        cursor[j] = excl;
        if (j < nn) {
            rowStart[node0 + j] = e0 + excl;
            normv[node0 + j] = (float)(1.0 / sqrt((double)(hist[j] + 1)));
        }
    }
    __syncthreads();
    for (int idx = t; idx < ne; idx += 256) {
        int v = staged[e0 + idx];
        int dl = v >> 17;
        int sn = v & 0x1FFFF;
        int r = atomicAdd(&cursor[dl], 1);
        colIdx[e0 + r] = sn;
    }
}

// ================================================== weight prep (tiny)
__global__ void wc_kernel(const float* __restrict__ Wp, const float* __restrict__ bp,
                          const float* __restrict__ W1, float* __restrict__ Wc,
                          float* __restrict__ bc) {
    int r = blockIdx.x;
    int cc = threadIdx.x;
    float acc = 0.f;
    if (r < 256) {
        for (int k = 0; k < 128; ++k) acc = fmaf(Wp[r * 128 + k], W1[k * 128 + cc], acc);
        Wc[r * 128 + cc] = acc;
    } else {
        for (int k = 0; k < 128; ++k) acc = fmaf(bp[k], W1[k * 128 + cc], acc);
        bc[cc] = acc;
    }
}

// transpose + f16 hi/lo split: W[K][128] -> Oh/Ol[128][K]
__global__ void tsplit_kernel(const float* __restrict__ W, _Float16* __restrict__ Oh,
                              _Float16* __restrict__ Ol, int K) {
    int id = blockIdx.x * 256 + threadIdx.x;
    if (id >= K * 128) return;
    int n = id / K;
    int k = id - n * K;
    float v = W[k * 128 + n];
    _Float16 h = (_Float16)v;
    Oh[id] = h;
    Ol[id] = (_Float16)(v - (float)h);
}

// =============================================== split-f16 MFMA GEMM (hybrid)
// C[r][c] = (sum_k A[r][k]*B[k][c] + bias[c]) * scale[r], C stored fp16 or fp32.
// 128 rows/block, 4 waves in 2x2; wave = 64 rows x 64 cols = 4mt x 4nt 16x16 tiles.
// B hi/lo double-buffered in LDS, ONE barrier per K-slab; next-slab global loads
// issued before the MFMA burst. launch_bounds(256,2): VGPR budget 256 so the
// prefetch register sets actually stay resident (R6-R8: default heuristic
// capped at 84/56 VGPRs and serialized every load).
template <bool AF16, int K>
__global__ __launch_bounds__(256, 2) void mfma_gemm(const float* __restrict__ Af,
                                                    const _Float16* __restrict__ Ah,
                                                    const _Float16* __restrict__ Bth,
                                                    const _Float16* __restrict__ Btl,
                                                    const float* __restrict__ bias,
                                                    const float* __restrict__ scale,
                                                    float* __restrict__ Cf,
                                                    _Float16* __restrict__ Ch,
                                                    int M) {
    constexpr int NSLAB = K / 32;
    __shared__ _Float16 sBh[2][128 * 40];
    __shared__ _Float16 sBl[2][128 * 40];

    const int t = threadIdx.x;
    const int w = t >> 6;
    const int wm = w & 1;          // wave row 0..1
    const int wn = w >> 1;         // wave col 0..1
    const int lane = t & 63;
    const int q = lane >> 4;       // quad -> k = q*8 + j
    const int mr = lane & 15;
    const int row0 = blockIdx.x * 128 + wm * 64;
    const int col0 = wn * 64;

    // ---- B staging assignment: lane covers n = t>>1, k-halves [seg*16, seg*16+16)
    const int sn = t >> 1;
    const int sseg = t & 1;
    const _Float16* gBh = Bth + (size_t)sn * K + sseg * 16;
    const _Float16* gBl = Btl + (size_t)sn * K + sseg * 16;
    const int swoff = sn * 40 + sseg * 16;

    // ---- A row addresses (clamped; stores guarded)
    int arow[4];
#pragma unroll
    for (int mt = 0; mt < 4; ++mt) {
        int r = row0 + mt * 16 + mr;
        arow[mt] = (r < M) ? r : (M - 1);
    }

    f32x4 acc[4][4];
#pragma unroll
    for (int mt = 0; mt < 4; ++mt)
#pragma unroll
        for (int nt = 0; nt < 4; ++nt) acc[mt][nt] = (f32x4){0.f, 0.f, 0.f, 0.f};

    // ---- prologue: stage slab 0 of B; prefetch A slab 0
    {
        half8 h0 = *(const half8*)(gBh);
        half8 h1 = *(const half8*)(gBh + 8);
        half8 l0 = *(const half8*)(gBl);
        half8 l1 = *(const half8*)(gBl + 8);
        *(half8*)&sBh[0][swoff] = h0;
        *(half8*)&sBh[0][swoff + 8] = h1;
        *(half8*)&sBl[0][swoff] = l0;
        *(half8*)&sBl[0][swoff + 8] = l1;
    }
    float4 aPre0[4], aPre1[4];   // fp32 path prefetch
    half8  aPreH[4];             // f16 path prefetch
#pragma unroll
    for (int mt = 0; mt < 4; ++mt) {
        if constexpr (AF16) {
            aPreH[mt] = *(const half8*)(Ah + (size_t)arow[mt] * K + q * 8);
        } else {
            const float* ap = Af + (size_t)arow[mt] * K + q * 8;
            aPre0[mt] = *(const float4*)ap;
            aPre1[mt] = *(const float4*)(ap + 4);
        }
    }
    __syncthreads();

#pragma unroll
    for (int s = 0; s < NSLAB; ++s) {
        const int cur = s & 1;
        const int nxt = 1 - cur;

        // ---- convert/settle current A fragments
        half8 ah[4], al[4];
#pragma unroll
        for (int mt = 0; mt < 4; ++mt) {
            if constexpr (AF16) {
                ah[mt] = aPreH[mt];
            } else {
                float av[8] = {aPre0[mt].x, aPre0[mt].y, aPre0[mt].z, aPre0[mt].w,
                               aPre1[mt].x, aPre1[mt].y, aPre1[mt].z, aPre1[mt].w};
#pragma unroll
                for (int j = 0; j < 8; ++j) {
                    _Float16 h = (_Float16)av[j];
                    ah[mt][j] = h;
                    al[mt][j] = (_Float16)(av[j] - (float)h);
                }
            }
        }

        // ---- issue next-slab global loads (fly under the MFMA burst)
        half8 nh0, nh1, nl0, nl1;
        if (s + 1 < NSLAB) {
            const int ko = (s + 1) * 32;
            nh0 = *(const half8*)(gBh + ko);
            nh1 = *(const half8*)(gBh + ko + 8);
            nl0 = *(const half8*)(gBl + ko);
            nl1 = *(const half8*)(gBl + ko + 8);
#pragma unroll
            for (int mt = 0; mt < 4; ++mt) {
                if constexpr (AF16) {
                    aPreH[mt] = *(const half8*)(Ah + (size_t)arow[mt] * K + ko + q * 8);
                } else {
                    const float* ap = Af + (size_t)arow[mt] * K + ko + q * 8;
                    aPre0[mt] = *(const float4*)ap;
                    aPre1[mt] = *(const float4*)(ap + 4);
                }
            }
        }

        // ---- B fragments from LDS
        half8 bh[4], bl[4];
#pragma unroll
        for (int nt = 0; nt < 4; ++nt) {
            int n = col0 + nt * 16 + mr;
            bh[nt] = *(half8*)&sBh[cur][n * 40 + q * 8];
            bl[nt] = *(half8*)&sBl[cur][n * 40 + q * 8];
        }

        // ---- MFMA burst
#pragma unroll
        for (int mt = 0; mt < 4; ++mt)
#pragma unroll
            for (int nt = 0; nt < 4; ++nt) {
                acc[mt][nt] = __builtin_amdgcn_mfma_f32_16x16x32_f16(ah[mt], bh[nt], acc[mt][nt], 0, 0, 0);
                acc[mt][nt] = __builtin_amdgcn_mfma_f32_16x16x32_f16(ah[mt], bl[nt], acc[mt][nt], 0, 0, 0);
                if constexpr (!AF16)
                    acc[mt][nt] = __builtin_amdgcn_mfma_f32_16x16x32_f16(al[mt], bh[nt], acc[mt][nt], 0, 0, 0);
            }

        // ---- commit next B slab to the other buffer, then barrier
        if (s + 1 < NSLAB) {
            *(half8*)&sBh[nxt][swoff] = nh0;
            *(half8*)&sBh[nxt][swoff + 8] = nh1;
            *(half8*)&sBl[nxt][swoff] = nl0;
            *(half8*)&sBl[nxt][swoff + 8] = nl1;
            __syncthreads();
        }
    }

    // ---- epilogue: C/D layout col=lane&15 (=mr), row=q*4+reg
#pragma unroll
    for (int mt = 0; mt < 4; ++mt) {
#pragma unroll
        for (int r = 0; r < 4; ++r) {
            int row = row0 + mt * 16 + q * 4 + r;
            if (row >= M) continue;
            float sc = scale[row];
#pragma unroll
            for (int nt = 0; nt < 4; ++nt) {
                int col = col0 + nt * 16 + mr;
                float bv = bias ? bias[col] : 0.f;
                float val = (acc[mt][nt][r] + bv) * sc;
                if (Ch) Ch[(size_t)row * 128 + col] = (_Float16)val;
                else    Cf[(size_t)row * 128 + col] = val;
            }
        }
    }
}

// ------------------------------------------------------------- aggregation
// zs fp16 pre-scaled by norm[row]. out = maybe_relu(norm[i]*(sum zs[src]+zs[i])+b)
__global__ __launch_bounds__(256) void agg_kernel(const _Float16* __restrict__ zs,
                                                  const int* __restrict__ rowStart,
                                                  const int* __restrict__ colIdx,
                                                  const float* __restrict__ normv,
                                                  const float* __restrict__ bias,
                                                  float* __restrict__ outF,
                                                  _Float16* __restrict__ outH,
                                                  int doRelu) {
    int wid = (blockIdx.x * 256 + threadIdx.x) >> 6;
    int lane = threadIdx.x & 63;
    if (wid >= N_NODES) return;
    int s0 = rowStart[wid];
    int s1 = rowStart[wid + 1];
    const int c = lane * 2;
    const _Float16* zc = zs + c;

    float2 a0 = make_float2(0.f, 0.f), a1 = a0, a2 = a0, a3 = a0;
    int e = s0;
    for (; e + 8 <= s1; e += 8) {
        int i0 = colIdx[e + 0], i1 = colIdx[e + 1], i2 = colIdx[e + 2], i3 = colIdx[e + 3];
        int i4 = colIdx[e + 4], i5 = colIdx[e + 5], i6 = colIdx[e + 6], i7 = colIdx[e + 7];
        half2v v0 = *(const half2v*)(zc + (size_t)i0 * 128);
        half2v v1 = *(const half2v*)(zc + (size_t)i1 * 128);
        half2v v2 = *(const half2v*)(zc + (size_t)i2 * 128);
        half2v v3 = *(const half2v*)(zc + (size_t)i3 * 128);
        half2v v4 = *(const half2v*)(zc + (size_t)i4 * 128);
        half2v v5 = *(const half2v*)(zc + (size_t)i5 * 128);
        half2v v6 = *(const half2v*)(zc + (size_t)i6 * 128);
        half2v v7 = *(const half2v*)(zc + (size_t)i7 * 128);
        a0.x += (float)v0[0] + (float)v4[0]; a0.y += (float)v0[1] + (float)v4[1];
        a1.x += (float)v1[0] + (float)v5[0]; a1.y += (float)v1[1] + (float)v5[1];
        a2.x += (float)v2[0] + (float)v6[0]; a2.y += (float)v2[1] + (float)v6[1];
        a3.x += (float)v3[0] + (float)v7[0]; a3.y += (float)v3[1] + (float)v7[1];
    }
    if (e + 4 <= s1) {
        int i0 = colIdx[e + 0], i1 = colIdx[e + 1], i2 = colIdx[e + 2], i3 = colIdx[e + 3];
        half2v v0 = *(const half2v*)(zc + (size_t)i0 * 128);
        half2v v1 = *(const half2v*)(zc + (size_t)i1 * 128);
        half2v v2 = *(const half2v*)(zc + (size_t)i2 * 128);
        half2v v3 = *(const half2v*)(zc + (size_t)i3 * 128);
        a0.x += (float)v0[0]; a0.y += (float)v0[1];
        a1.x += (float)v1[0]; a1.y += (float)v1[1];
        a2.x += (float)v2[0]; a2.y += (float)v2[1];
        a3.x += (float)v3[0]; a3.y += (float)v3[1];
        e += 4;
    }
    for (; e < s1; ++e) {
        int i0 = colIdx[e];
        half2v v0 = *(const half2v*)(zc + (size_t)i0 * 128);
        a0.x += (float)v0[0]; a0.y += (float)v0[1];
    }

    half2v self = *(const half2v*)(zc + (size_t)wid * 128);
    float sx = (a0.x + a1.x) + (a2.x + a3.x) + (float)self[0];
    float sy = (a0.y + a1.y) + (a2.y + a3.y) + (float)self[1];
    float nd = normv[wid];
    float2 bv = *(const float2*)(bias + c);
    float ox = fmaf(nd, sx, bv.x);
    float oy = fmaf(nd, sy, bv.y);
    if (doRelu) {
        ox = fmaxf(ox, 0.f);
        oy = fmaxf(oy, 0.f);
    }
    if (outH) {
        half2v o;
        o[0] = (_Float16)ox;
        o[1] = (_Float16)oy;
        *(half2v*)(outH + (size_t)wid * 128 + c) = o;
    } else {
        *(float2*)(outF + (size_t)wid * 128 + c) = make_float2(ox, oy);
    }
}

// ---------------------------------------------------------------- launcher
extern "C" void kernel_launch(void* const* d_in, const int* in_sizes, int n_in,
                              void* d_out, int out_size, void* d_ws, size_t ws_size,
                              hipStream_t stream) {
    const float* x  = (const float*)d_in[0];
    const int* ei   = (const int*)d_in[1];
    const float* Wp = (const float*)d_in[2];
    const float* bp = (const float*)d_in[3];
    const float* W1 = (const float*)d_in[4];
    const float* b1 = (const float*)d_in[5];
    const float* W2 = (const float*)d_in[6];
    const float* b2 = (const float*)d_in[7];
    float* out = (float*)d_out;

    const int* srcIdx = ei;
    const int* dstIdx = ei + N_EDGES;

    size_t off = 0;
    auto alloc = [&](size_t bytes) -> void* {
        void* p = (char*)d_ws + off;
        off += (bytes + 511) & ~(size_t)511;
        return p;
    };
    int* rowStart   = (int*)alloc((size_t)(N_NODES + 1) * 4);
    int* colIdx     = (int*)alloc((size_t)N_EDGES * 4);
    int* staged     = (int*)alloc((size_t)N_EDGES * 4);
    int* bbc        = (int*)alloc((size_t)NBUCK * NCHUNK * 4);
    int* bucketOff  = (int*)alloc((size_t)(NBUCK + 1) * 4);
    float* normv    = (float*)alloc((size_t)N_NODES * 4);
    float* Wc       = (float*)alloc((size_t)256 * 128 * 4);
    float* bc       = (float*)alloc((size_t)128 * 4);
    _Float16* Wcth  = (_Float16*)alloc((size_t)128 * 256 * 2);
    _Float16* Wctl  = (_Float16*)alloc((size_t)128 * 256 * 2);
    _Float16* W2th  = (_Float16*)alloc((size_t)128 * 128 * 2);
    _Float16* W2tl  = (_Float16*)alloc((size_t)128 * 128 * 2);
    _Float16* zA    = (_Float16*)alloc((size_t)N_NODES * 128 * 2);
    _Float16* zB    = (_Float16*)alloc((size_t)N_NODES * 128 * 2);

    const int GB = (N_NODES + 127) / 128;  // 782 (128 rows/block)
    const int AB = (N_NODES + 3) / 4;      // 25000

    // ---- CSR build (bucketed counting sort) ----
    b1_hist<<<NCHUNK, 256, 0, stream>>>(dstIdx, bbc);
    b_scan<<<1, 256, 0, stream>>>(bbc, bucketOff, rowStart);
    b2_scatter<<<NCHUNK, 256, 0, stream>>>(srcIdx, dstIdx, bbc, bucketOff, staged);
    b3_sort<<<NBUCK, 256, 0, stream>>>(staged, bucketOff, rowStart, normv, colIdx);

    // ---- weight prep ----
    wc_kernel<<<257, 128, 0, stream>>>(Wp, bp, W1, Wc, bc);
    tsplit_kernel<<<(256 * 128 + 255) / 256, 256, 0, stream>>>(Wc, Wcth, Wctl, 256);
    tsplit_kernel<<<(128 * 128 + 255) / 256, 256, 0, stream>>>(W2, W2th, W2tl, 128);

    // ---- pipeline (all intermediates fp16, pre-scaled by norm) ----
    // zA = f16[(x @ Wc + bc) * norm]
    mfma_gemm<false, 256><<<GB, 256, 0, stream>>>(x, nullptr, Wcth, Wctl, bc, normv,
                                                  nullptr, zA, N_NODES);
    // zB = f16[relu(norm*(sum zA[src] + zA[self]) + b1)]
    agg_kernel<<<AB, 256, 0, stream>>>(zA, rowStart, colIdx, normv, b1, nullptr, zB, 1);
    // zA (reused) = f16[(zB @ W2) * norm]   — A fp16, 2-product path
    mfma_gemm<true, 128><<<GB, 256, 0, stream>>>(nullptr, zB, W2th, W2tl, nullptr, normv,
                                                 nullptr, zA, N_NODES);
    // out = fp32[norm*(sum zA[src] + zA[self]) + b2]
    agg_kernel<<<AB, 256, 0, stream>>>(zA, rowStart, colIdx, normv, b2, out, nullptr, 0);
}